// Round 6
// baseline (81.799 us; speedup 1.0000x reference)
//
#include <hip/hip_runtime.h>

// PolynomialRegression via bf16 MFMA, SINGLE launch.
//   y[b][o] = bias_o + sum_i x[b][i] * ( (U_o x[b])_i + W1[o][i] )
// History: R7 2-launch 69.3 | R8 fused on-the-fly W-pack, 64-row 69.8 |
//   R11 32-row 73.4 (2x W traffic) | R12 128-row 71.5 (occupancy 12->8
//   waves/CU + 1.25 blocks/CU imbalance ate the traffic win).
// U-shape around 64-row. Timed window = 41 us poison fill (flushes L2/L3,
//   immovable) + ~28 us kernel+gaps. All confound-free levers exhausted
//   except per-block fixed-cost amortization.
// R13: 64-row tile, TWO o's per block processed sequentially (grid (64,5) =
//   320 blocks, all resident at LB(256,3), 12 waves/CU unchanged, W traffic
//   unchanged 94 MB, acc[4][4] reused per o). x-staging + block ramp halved.
//   o1 chunk-0 B-frags prefetched under o0's epilogue.
// Predict: absmax 0.03125; dur 67.5-69 if staging/ramp real; neutral ->
//   declare harness floor.

#define DD 256
#define NF 33153
#define TPB 256
#define MROWS 64
#define ASTRIDE 264   // bf16 elems; 528 B row stride -> 2-way LDS alias (free)

typedef __attribute__((ext_vector_type(8))) short short8;
typedef __attribute__((ext_vector_type(4))) float floatx4;
typedef __attribute__((ext_vector_type(4), aligned(4))) float float4a;

union S8U { unsigned u[4]; short8 s; };

__device__ inline unsigned pack2(float lo, float hi) {   // 2xfp32 -> bf16x2, half-up
    unsigned a = __builtin_bit_cast(unsigned, hi) + 0x8000u;
    unsigned b = __builtin_bit_cast(unsigned, lo) + 0x8000u;
    return __builtin_amdgcn_perm(a, b, 0x07060302u);
}

// 8 consecutive fp32 -> short8 of bf16 (dword-aligned source suffices).
__device__ inline short8 load_pack8(const float* __restrict__ p) {
    float4a v0 = *(const float4a*)p;
    float4a v1 = *(const float4a*)(p + 4);
    S8U r;
    r.u[0] = pack2(v0.x, v0.y); r.u[1] = pack2(v0.z, v0.w);
    r.u[2] = pack2(v1.x, v1.y); r.u[3] = pack2(v1.z, v1.w);
    return r.s;
}

// Packed upper-triangular: element (i,j), j>=i, lives at W[o*NF + troff(i) + j].
// For j<i this reads in-bounds garbage from earlier rows (masked to zero).
__device__ inline int troff(int i) { return 257 + 255 * i - ((i * (i - 1)) >> 1); }

__global__ __launch_bounds__(TPB, 3)
void PolynomialRegression_75385265979710_kernel(const float* __restrict__ x,
                                                const float* __restrict__ W,
                                                float* __restrict__ out) {
    __shared__ __align__(16) unsigned short As[MROWS * ASTRIDE];  // 33792 B
    __shared__ float red[4 * MROWS];                              // 1024 B

    const int tid  = threadIdx.x;
    const int lane = tid & 63, wave = tid >> 6;      // 4 waves
    const int ln   = lane & 15, quad = lane >> 4;
    const int q8   = quad * 8;
    const int rowbase = blockIdx.x * MROWS;
    const int o0 = blockIdx.y * 2;                   // this block's o-pair
    const int g1 = wave, g2 = 7 - wave;              // wave owns 2 groups
    const int rem = 8 - wave;                        // chunks in group g1

    // --- stage x-tile (64 x 256) fp32 -> bf16 into padded LDS (ONCE) ---
#pragma unroll
    for (int it = 0; it < 8; ++it) {
        int idx = it * 2048 + tid * 8;
        int r = idx >> 8, c = idx & 255;
        const float* src = &x[(rowbase + r) * DD + c];
        float4a v0 = *(const float4a*)src;
        float4a v1 = *(const float4a*)(src + 4);
        S8U p;
        p.u[0] = pack2(v0.x, v0.y); p.u[1] = pack2(v0.z, v0.w);
        p.u[2] = pack2(v1.x, v1.y); p.u[3] = pack2(v1.z, v1.w);
        *(short8*)&As[r * ASTRIDE + c] = p.s;
    }

    // per-lane W offsets for this wave's 4 B-rows (o-independent)
    const int offA0 = troff(g1 * 32 + ln)      + q8;
    const int offA1 = troff(g1 * 32 + 16 + ln) + q8;
    const int offB0 = troff(g2 * 32 + ln)      + q8;
    const int offB1 = troff(g2 * 32 + 16 + ln) + q8;

    // diagonal-chunk zero masks (o-independent; b0 row = ln, b1 row = 16+ln;
    // zero where col < row).
    unsigned mA[4], mB[4];
#pragma unroll
    for (int w2 = 0; w2 < 4; ++w2) {
        mA[w2] = ((q8 + 2 * w2     < ln) ? 0u : 0x0000FFFFu)
               | ((q8 + 2 * w2 + 1 < ln) ? 0u : 0xFFFF0000u);
        mB[w2] = ((q8 + 2 * w2     < 16 + ln) ? 0u : 0x0000FFFFu)
               | ((q8 + 2 * w2 + 1 < 16 + ln) ? 0u : 0xFFFF0000u);
    }

    // epilogue row indices (o-independent)
    int iRow[4];
#pragma unroll
    for (int nt = 0; nt < 4; ++nt) {
        int g = (nt < 2) ? g1 : g2;
        iRow[nt] = g * 32 + (nt & 1) * 16 + ln;
    }

    // prefetch o0 chunk t=0 (kc=g1, diagonal) B-frags: overlaps staging+barrier
    S8U pb0, pb1;
    pb0.s = load_pack8(W + o0 * NF + offA0 + g1 * 32);
    pb1.s = load_pack8(W + o0 * NF + offA1 + g1 * 32);

    __syncthreads();

#pragma unroll
    for (int oo = 0; oo < 2; ++oo) {
        const int o = o0 + oo;
        const float* __restrict__ Wo = W + o * NF;

        float w1v[4];
#pragma unroll
        for (int nt = 0; nt < 4; ++nt) w1v[nt] = Wo[1 + iRow[nt]];
        const float bias = Wo[0];

        floatx4 acc[4][4];   // [m_tile][n_tile: 0,1 = g1; 2,3 = g2]
#pragma unroll
        for (int mt = 0; mt < 4; ++mt)
#pragma unroll
            for (int nt = 0; nt < 4; ++nt) acc[mt][nt] = (floatx4)0.f;

        // --- uniform 9-chunk loop, fully unrolled ---
#pragma unroll
        for (int t = 0; t < 9; ++t) {
            const bool first = (t < rem);                      // wave-uniform
            const int kc = first ? (g1 + t) : (g2 + (t - rem));
            const int co = kc * 32;
            S8U b0, b1;
            if (t == 0) {            // prefetched
                b0 = pb0; b1 = pb1;
            } else {
                b0.s = load_pack8(Wo + (first ? offA0 : offB0) + co);
                b1.s = load_pack8(Wo + (first ? offA1 : offB1) + co);
            }
            if (t == 0 || t == rem) {                          // diagonal chunk
#pragma unroll
                for (int w2 = 0; w2 < 4; ++w2) { b0.u[w2] &= mA[w2]; b1.u[w2] &= mB[w2]; }
            }
            short8 a[4];
#pragma unroll
            for (int mt = 0; mt < 4; ++mt)
                a[mt] = *(const short8*)&As[(mt * 16 + ln) * ASTRIDE + co + q8];
            if (first) {
#pragma unroll
                for (int mt = 0; mt < 4; ++mt) {
                    acc[mt][0] = __builtin_amdgcn_mfma_f32_16x16x32_bf16(a[mt], b0.s, acc[mt][0], 0, 0, 0);
                    acc[mt][1] = __builtin_amdgcn_mfma_f32_16x16x32_bf16(a[mt], b1.s, acc[mt][1], 0, 0, 0);
                }
            } else {
#pragma unroll
                for (int mt = 0; mt < 4; ++mt) {
                    acc[mt][2] = __builtin_amdgcn_mfma_f32_16x16x32_bf16(a[mt], b0.s, acc[mt][2], 0, 0, 0);
                    acc[mt][3] = __builtin_amdgcn_mfma_f32_16x16x32_bf16(a[mt], b1.s, acc[mt][3], 0, 0, 0);
                }
            }
        }

        // prefetch o1 chunk t=0 under o0's epilogue
        if (oo == 0) {
            pb0.s = load_pack8(W + (o0 + 1) * NF + offA0 + g1 * 32);
            pb1.s = load_pack8(W + (o0 + 1) * NF + offA1 + g1 * 32);
        }

        // --- epilogue: y_part[m] = sum_{i in wave's set} x[m][i]*(T[m][i]+W1[o][i])
#pragma unroll
        for (int mt = 0; mt < 4; ++mt) {
#pragma unroll
            for (int r = 0; r < 4; ++r) {
                const int m = mt * 16 + quad * 4 + r;   // C/D: row=quad*4+reg, col=ln
                float p = 0.f;
#pragma unroll
                for (int nt = 0; nt < 4; ++nt) {
                    unsigned u = As[m * ASTRIDE + iRow[nt]];
                    float xv = __builtin_bit_cast(float, u << 16);
                    p = fmaf(xv, acc[mt][nt][r] + w1v[nt], p);
                }
                p += __shfl_xor(p, 1);
                p += __shfl_xor(p, 2);
                p += __shfl_xor(p, 4);
                p += __shfl_xor(p, 8);
                if (ln == 0) red[wave * MROWS + m] = p;   // 4 partials
            }
        }
        __syncthreads();

        if (tid < MROWS) {
            float s = bias;
#pragma unroll
            for (int w = 0; w < 4; ++w) s += red[w * MROWS + tid];
            out[(rowbase + tid) * 10 + o] = s;
        }
        __syncthreads();   // protect red[] before next o's writes
    }
}

extern "C" void kernel_launch(void* const* d_in, const int* in_sizes, int n_in,
                              void* d_out, int out_size, void* d_ws, size_t ws_size,
                              hipStream_t stream) {
    const float* x = (const float*)d_in[0];   // (4096, 256)
    const float* W = (const float*)d_in[1];   // (10, 33153)
    float* out = (float*)d_out;               // (4096, 10)

    dim3 grid(4096 / MROWS, 5);               // 64 x 5 = 320 blocks, 2 o's each
    PolynomialRegression_75385265979710_kernel<<<grid, TPB, 0, stream>>>(x, W, out);
}

// Round 7
// 69.415 us; speedup vs baseline: 1.1784x; 1.1784x over previous
//
#include <hip/hip_runtime.h>

// PolynomialRegression via bf16 MFMA, SINGLE launch.
//   y[b][o] = bias_o + sum_i x[b][i] * ( (U_o x[b])_i + W1[o][i] )
// History: R7 2-launch 69.3 | R8 fused on-the-fly W-pack 64-row 69.8 |
//   R11 32-row 73.4 | R12 128-row 71.5 | R13 2-o-per-block 81.8 (serialized,
//   halved concurrency — reverted).
// R13's cold-dispatch counters: FETCH 12.6 MB (W re-reads are L2-resident,
//   never HBM), MfmaUtil/VALUBusy ~0 -> kernel time is stall, not issue.
//   Binding chain: per K-chunk global_load(W)->vmcnt->pack->MFMA, only t=0
//   prefetched -> ~8 x ~300cyc unhidden L2 latency per o-pass.
// R14: R8 config (64-row, grid (64,10)=640 blocks, acc[4][4], LB(256,3))
//   + depth-1 software pipeline on B loads: issue raw float4a loads for
//   chunk t+1 before packing/consuming chunk t (T14 issue-early pattern).
//   +16 VGPR of pipeline state, same occupancy bucket. Numerics identical.
// Predict: absmax 0.03125; dur 69.8 -> 65-67 if K-loop-latency-bound;
//   neutral -> stall is in staging/epilogue.

#define DD 256
#define NF 33153
#define TPB 256
#define MROWS 64
#define ASTRIDE 264   // bf16 elems; 528 B row stride -> 2-way LDS alias (free)

typedef __attribute__((ext_vector_type(8))) short short8;
typedef __attribute__((ext_vector_type(4))) float floatx4;
typedef __attribute__((ext_vector_type(4), aligned(4))) float float4a;

union S8U { unsigned u[4]; short8 s; };

__device__ inline unsigned pack2(float lo, float hi) {   // 2xfp32 -> bf16x2, half-up
    unsigned a = __builtin_bit_cast(unsigned, hi) + 0x8000u;
    unsigned b = __builtin_bit_cast(unsigned, lo) + 0x8000u;
    return __builtin_amdgcn_perm(a, b, 0x07060302u);
}

// Packed upper-triangular: element (i,j), j>=i, lives at W[o*NF + troff(i) + j].
// For j<i this reads in-bounds garbage from earlier rows (masked to zero).
__device__ inline int troff(int i) { return 257 + 255 * i - ((i * (i - 1)) >> 1); }

__global__ __launch_bounds__(TPB, 3)
void PolynomialRegression_75385265979710_kernel(const float* __restrict__ x,
                                                const float* __restrict__ W,
                                                float* __restrict__ out) {
    __shared__ __align__(16) unsigned short As[MROWS * ASTRIDE];  // 33792 B
    __shared__ float red[4 * MROWS];                              // 1024 B

    const int tid  = threadIdx.x;
    const int lane = tid & 63, wave = tid >> 6;      // 4 waves
    const int ln   = lane & 15, quad = lane >> 4;
    const int q8   = quad * 8;
    const int rowbase = blockIdx.x * MROWS;
    const int o  = blockIdx.y;
    const int g1 = wave, g2 = 7 - wave;              // wave owns 2 groups
    const int rem = 8 - wave;                        // chunks in group g1

    const float* __restrict__ Wo = W + o * NF;

    // per-lane W offsets for this wave's 4 B-rows (abs column added later)
    const int offA0 = troff(g1 * 32 + ln)      + q8;
    const int offA1 = troff(g1 * 32 + 16 + ln) + q8;
    const int offB0 = troff(g2 * 32 + ln)      + q8;
    const int offB1 = troff(g2 * 32 + 16 + ln) + q8;

    // issue chunk t=0 raw B loads FIRST (deepest latency cover: whole staging)
    float4a ca0 = *(const float4a*)(Wo + offA0 + g1 * 32);
    float4a ca1 = *(const float4a*)(Wo + offA0 + g1 * 32 + 4);
    float4a cb0 = *(const float4a*)(Wo + offA1 + g1 * 32);
    float4a cb1 = *(const float4a*)(Wo + offA1 + g1 * 32 + 4);

    // --- stage x-tile (64 x 256) fp32 -> bf16 into padded LDS ---
#pragma unroll
    for (int it = 0; it < 8; ++it) {
        int idx = it * 2048 + tid * 8;
        int r = idx >> 8, c = idx & 255;
        const float* src = &x[(rowbase + r) * DD + c];
        float4a v0 = *(const float4a*)src;
        float4a v1 = *(const float4a*)(src + 4);
        S8U p;
        p.u[0] = pack2(v0.x, v0.y); p.u[1] = pack2(v0.z, v0.w);
        p.u[2] = pack2(v1.x, v1.y); p.u[3] = pack2(v1.z, v1.w);
        *(short8*)&As[r * ASTRIDE + c] = p.s;
    }

    // diagonal-chunk zero masks (col-in-tile = q8+e; b0 row = ln, b1 row =
    // 16+ln; zero where col < row). Group-independent.
    unsigned mA[4], mB[4];
#pragma unroll
    for (int w2 = 0; w2 < 4; ++w2) {
        mA[w2] = ((q8 + 2 * w2     < ln) ? 0u : 0x0000FFFFu)
               | ((q8 + 2 * w2 + 1 < ln) ? 0u : 0xFFFF0000u);
        mB[w2] = ((q8 + 2 * w2     < 16 + ln) ? 0u : 0x0000FFFFu)
               | ((q8 + 2 * w2 + 1 < 16 + ln) ? 0u : 0xFFFF0000u);
    }

    // hoisted epilogue constants (latency hides under K-loop)
    int iRow[4];
    float w1v[4];
#pragma unroll
    for (int nt = 0; nt < 4; ++nt) {
        int g = (nt < 2) ? g1 : g2;
        iRow[nt] = g * 32 + (nt & 1) * 16 + ln;
        w1v[nt]  = Wo[1 + iRow[nt]];
    }
    const float bias = Wo[0];

    __syncthreads();

    floatx4 acc[4][4];   // [m_tile][n_tile: 0,1 = group g1; 2,3 = group g2]
#pragma unroll
    for (int mt = 0; mt < 4; ++mt)
#pragma unroll
        for (int nt = 0; nt < 4; ++nt) acc[mt][nt] = (floatx4)0.f;

    // --- uniform 9-chunk loop, fully unrolled, depth-1 B-load pipeline:
    //     t<rem -> (g1, kc=g1+t), else -> (g2, kc=g2+(t-rem)).
    //     At chunk t: issue raw loads for t+1, THEN pack+consume chunk t.
#pragma unroll
    for (int t = 0; t < 9; ++t) {
        const bool first = (t < rem);                      // wave-uniform
        const int kc = first ? (g1 + t) : (g2 + (t - rem));
        const int co = kc * 32;

        // issue next chunk's raw loads (independent of this chunk's compute)
        float4a na0, na1, nb0, nb1;
        if (t < 8) {
            const bool nf = (t + 1 < rem);
            const int nkc = nf ? (g1 + t + 1) : (g2 + (t + 1 - rem));
            const int nco = nkc * 32;
            const float* p0 = Wo + (nf ? offA0 : offB0) + nco;
            const float* p1 = Wo + (nf ? offA1 : offB1) + nco;
            na0 = *(const float4a*)p0; na1 = *(const float4a*)(p0 + 4);
            nb0 = *(const float4a*)p1; nb1 = *(const float4a*)(p1 + 4);
        }

        // pack current chunk (data has been in flight for a full chunk)
        S8U b0, b1;
        b0.u[0] = pack2(ca0.x, ca0.y); b0.u[1] = pack2(ca0.z, ca0.w);
        b0.u[2] = pack2(ca1.x, ca1.y); b0.u[3] = pack2(ca1.z, ca1.w);
        b1.u[0] = pack2(cb0.x, cb0.y); b1.u[1] = pack2(cb0.z, cb0.w);
        b1.u[2] = pack2(cb1.x, cb1.y); b1.u[3] = pack2(cb1.z, cb1.w);

        if (t == 0 || t == rem) {                          // diagonal chunk
#pragma unroll
            for (int w2 = 0; w2 < 4; ++w2) { b0.u[w2] &= mA[w2]; b1.u[w2] &= mB[w2]; }
        }

        short8 a[4];
#pragma unroll
        for (int mt = 0; mt < 4; ++mt)
            a[mt] = *(const short8*)&As[(mt * 16 + ln) * ASTRIDE + co + q8];

        if (first) {
#pragma unroll
            for (int mt = 0; mt < 4; ++mt) {
                acc[mt][0] = __builtin_amdgcn_mfma_f32_16x16x32_bf16(a[mt], b0.s, acc[mt][0], 0, 0, 0);
                acc[mt][1] = __builtin_amdgcn_mfma_f32_16x16x32_bf16(a[mt], b1.s, acc[mt][1], 0, 0, 0);
            }
        } else {
#pragma unroll
            for (int mt = 0; mt < 4; ++mt) {
                acc[mt][2] = __builtin_amdgcn_mfma_f32_16x16x32_bf16(a[mt], b0.s, acc[mt][2], 0, 0, 0);
                acc[mt][3] = __builtin_amdgcn_mfma_f32_16x16x32_bf16(a[mt], b1.s, acc[mt][3], 0, 0, 0);
            }
        }

        if (t < 8) { ca0 = na0; ca1 = na1; cb0 = nb0; cb1 = nb1; }
    }

    // --- epilogue: y_part[m] = sum_{i in wave's set} x[m][i]*(T[m][i]+W1[o][i])
#pragma unroll
    for (int mt = 0; mt < 4; ++mt) {
#pragma unroll
        for (int r = 0; r < 4; ++r) {
            const int m = mt * 16 + quad * 4 + r;   // C/D: row=quad*4+reg, col=ln
            float p = 0.f;
#pragma unroll
            for (int nt = 0; nt < 4; ++nt) {
                unsigned u = As[m * ASTRIDE + iRow[nt]];
                float xv = __builtin_bit_cast(float, u << 16);
                p = fmaf(xv, acc[mt][nt][r] + w1v[nt], p);
            }
            p += __shfl_xor(p, 1);
            p += __shfl_xor(p, 2);
            p += __shfl_xor(p, 4);
            p += __shfl_xor(p, 8);
            if (ln == 0) red[wave * MROWS + m] = p;   // 4 waves -> 4 partials
        }
    }
    __syncthreads();

    if (tid < MROWS) {
        float s = bias;
#pragma unroll
        for (int w = 0; w < 4; ++w) s += red[w * MROWS + tid];
        out[(rowbase + tid) * 10 + o] = s;
    }
}

extern "C" void kernel_launch(void* const* d_in, const int* in_sizes, int n_in,
                              void* d_out, int out_size, void* d_ws, size_t ws_size,
                              hipStream_t stream) {
    const float* x = (const float*)d_in[0];   // (4096, 256)
    const float* W = (const float*)d_in[1];   // (10, 33153)
    float* out = (float*)d_out;               // (4096, 10)

    dim3 grid(4096 / MROWS, 10);              // 64 x 10 = 640 blocks
    PolynomialRegression_75385265979710_kernel<<<grid, TPB, 0, stream>>>(x, W, out);
}